// Round 8
// baseline (247.712 us; speedup 1.0000x reference)
//
#include <hip/hip_runtime.h>
#include <hip/hip_bf16.h>
#include <cstdint>
#include <cstddef>

typedef __attribute__((ext_vector_type(4))) float f32x4;
typedef __attribute__((ext_vector_type(8))) short bf16x8;
typedef unsigned short ushort_t;

#define KDIM 768
#define GQ 96        // KDIM/8 granules
#define BM 128
#define BN 256
#define NKT 24       // 768/32 K-steps

static __device__ __forceinline__ float sani(float x) {
  if (__builtin_isnan(x)) return 0.0f;
  if (__builtin_isinf(x)) return x > 0.0f ? 1.0e4f : -1.0e4f;
  return x;
}

static __device__ __forceinline__ unsigned short f2bf(float x) {
  unsigned u = __builtin_bit_cast(unsigned, x);
  unsigned r = 0x7FFFu + ((u >> 16) & 1u);
  return (unsigned short)((u + r) >> 16);
}

// xt: K-major-tiled A  [g 0..95][1024 rows][8 elems] bf16
// wt: K-major-tiled B  [g 0..95][Vpad rows][8 elems] bf16
// This makes every MFMA fragment a contiguous 16B-per-lane global load.

__global__ __launch_bounds__(256) void prep_x_kernel(
    const float* __restrict__ h, ushort_t* __restrict__ xt,
    float* __restrict__ tx) {
  const int row = blockIdx.x;
  const int t = threadIdx.x;
  const float* src = h + (size_t)row * (KDIM + 1) + 1;  // skip time comp
  float v0 = sani(src[t]);
  float v1 = sani(src[t + 256]);
  float v2 = sani(src[t + 512]);
  float ss = v0 * v0 + v1 * v1 + v2 * v2;
#pragma unroll
  for (int off = 32; off > 0; off >>= 1) ss += __shfl_down(ss, off);
  __shared__ float red[4];
  if ((t & 63) == 0) red[t >> 6] = ss;
  __syncthreads();
  if (t == 0) {
    float total = red[0] + red[1] + red[2] + red[3];
    tx[row] = sqrtf(1.0f + total);
  }
  int e;
  e = t;       xt[((size_t)(e >> 3) * 1024 + row) * 8 + (e & 7)] = f2bf(v0);
  e = t + 256; xt[((size_t)(e >> 3) * 1024 + row) * 8 + (e & 7)] = f2bf(v1);
  e = t + 512; xt[((size_t)(e >> 3) * 1024 + row) * 8 + (e & 7)] = f2bf(v2);
}

// 8 rows per block: stage raw f32 in LDS, row-norms, exp-map scale, write
// 16B chunks of wt (consecutive rows contiguous -> coalesced 128B segments).
__global__ __launch_bounds__(256) void prep_w_kernel(
    const float* __restrict__ w, ushort_t* __restrict__ wt,
    float* __restrict__ cw, int V, int Vpad) {
  __shared__ float fs[8 * KDIM];  // 24 KB
  __shared__ float redv[8], scs[8];
  const int t = threadIdx.x;
  const int r = t >> 5, j = t & 31;
  const int row = blockIdx.x * 8 + r;
  const bool valid = row < V;
  const float* src = w + (size_t)row * KDIM;
  float ss = 0.0f;
#pragma unroll
  for (int k = 0; k < 24; ++k) {
    float v = valid ? src[j + 32 * k] : 0.0f;
    fs[r * KDIM + j + 32 * k] = v;
    ss = fmaf(v, v, ss);
  }
#pragma unroll
  for (int m = 16; m > 0; m >>= 1) ss += __shfl_xor(ss, m);  // within 32-group
  if (j == 0) redv[r] = ss;
  __syncthreads();
  if (t < 8) {
    const int rw = blockIdx.x * 8 + t;
    float rr = sqrtf(redv[t]);
    float rc = fminf(rr, 3.0f);
    float e = expf(rc), ei = 1.0f / e;
    scs[t] = (rw < V) ? 0.5f * (e - ei) / fmaxf(rr, 1e-8f) : 0.0f;
    cw[rw] = (rw < V) ? sani(0.5f * (e + ei)) : 0.0f;
  }
  __syncthreads();
#pragma unroll
  for (int p = 0; p < 3; ++p) {
    const int c = t + 256 * p;   // 768 chunks: g = c>>3, local row = c&7
    const int g = c >> 3, rl = c & 7;
    const float sc = scs[rl];
    ushort_t pk[8];
#pragma unroll
    for (int e = 0; e < 8; ++e)
      pk[e] = f2bf(sani(fs[rl * KDIM + g * 8 + e] * sc));
    *(uint4*)&wt[((size_t)g * Vpad + blockIdx.x * 8 + rl) * 8] =
        *(const uint4*)pk;
  }
}

// No-LDS register GEMM: 4 waves (each 128M x 64N), fragments loaded
// global->VGPR (A from L1/L2-resident xt, B streamed from wt), double-
// buffered one K-step ahead. No barriers, no LDS, no explicit waitcnt —
// compiler schedules the reg pipeline; 2 waves/SIMD hide latency.
__global__ __launch_bounds__(256, 2) void gemm_kernel(
    const ushort_t* __restrict__ xt, const ushort_t* __restrict__ wt,
    const float* __restrict__ tx, const float* __restrict__ cw,
    const float* __restrict__ ls, float* __restrict__ out,
    int V, int Vpad, int nwg8) {
  const int tid = threadIdx.x;
  const int lane = tid & 63;
  const int wc = tid >> 6;  // 0..3: wave owns 64 N-cols
  const int l15 = lane & 15;
  const int lq = lane >> 4;

  // chunked XCD swizzle; consecutive L share bn (B-panel per XCD L2)
  const int g = blockIdx.x;
  const int L = (g & 7) * nwg8 + (g >> 3);
  const int bm = L & 7;   // 8 M-tiles
  const int bn = L >> 3;

  const int a_row0 = bm * BM;
  const int b_row0 = bn * BN + wc * 64;

  // fragment base pointers: frag(t, i) = base + t*granule_stride + i*128 elems
  const ushort_t* ap = xt + ((size_t)lq * 1024 + a_row0 + l15) * 8;
  const ushort_t* bp = wt + ((size_t)lq * Vpad + b_row0 + l15) * 8;
  const size_t astep = (size_t)4 * 1024 * 8;  // 4 granules per K-step
  const size_t bstep = (size_t)4 * Vpad * 8;

#define LOADA(T_, D_)                                                         \
  _Pragma("unroll") for (int mi = 0; mi < 8; ++mi)                            \
      D_[mi] = *(const bf16x8*)(ap + (size_t)(T_) * astep + mi * 128);
#define LOADB(T_, D_)                                                         \
  _Pragma("unroll") for (int ni = 0; ni < 4; ++ni)                            \
      D_[ni] = *(const bf16x8*)(bp + (size_t)(T_) * bstep + ni * 128);
#define STEP(AF_, BF_)                                                        \
  _Pragma("unroll") for (int mi = 0; mi < 8; ++mi)                            \
    _Pragma("unroll") for (int ni = 0; ni < 4; ++ni)                          \
        acc[mi][ni] = __builtin_amdgcn_mfma_f32_16x16x32_bf16(                \
            BF_[ni], AF_[mi], acc[mi][ni], 0, 0, 0);

  f32x4 acc[8][4];
#pragma unroll
  for (int i = 0; i < 8; ++i)
#pragma unroll
    for (int j = 0; j < 4; ++j) acc[i][j] = (f32x4){0.f, 0.f, 0.f, 0.f};

  bf16x8 afA[8], afB[8], bfA[4], bfB[4];
  LOADA(0, afA);
  LOADB(0, bfA);
#pragma unroll
  for (int tt = 0; tt < NKT / 2; ++tt) {
    const int t1 = 2 * tt + 1;
    LOADA(t1, afB);
    LOADB(t1, bfB);
    STEP(afA, bfA);
    if (t1 + 1 < NKT) {
      LOADA(t1 + 1, afA);
      LOADB(t1 + 1, bfA);
    }
    STEP(afB, bfB);
  }

  float tau = ls[0];
  tau = fminf(fmaxf(tau, 0.01f), 2.5f);

  // swapped-operand C/D: m = l15 (col field), n = lq*4 + j (row field)
#pragma unroll
  for (int mi = 0; mi < 8; ++mi) {
    const int mg = a_row0 + mi * 16 + l15;
    const float txm = tx[mg];
    float* orow = out + (size_t)mg * V;
#pragma unroll
    for (int ni = 0; ni < 4; ++ni) {
      const int nb = b_row0 + ni * 16 + lq * 4;
      const f32x4 cw4 = *(const f32x4*)&cw[nb];
      f32x4 v;
#pragma unroll
      for (int j = 0; j < 4; ++j)
        v[j] = (acc[mi][ni][j] - txm * cw4[j]) * tau;
      if (nb + 3 < V) {
        __builtin_memcpy(&orow[nb], &v, 16);
      } else {
#pragma unroll
        for (int j = 0; j < 4; ++j)
          if (nb + j < V) orow[nb + j] = v[j];
      }
    }
  }
#undef LOADA
#undef LOADB
#undef STEP
}

extern "C" void kernel_launch(void* const* d_in, const int* in_sizes, int n_in,
                              void* d_out, int out_size, void* d_ws, size_t ws_size,
                              hipStream_t stream) {
  const float* h = (const float*)d_in[0];
  const float* w = (const float*)d_in[1];
  const float* ls = (const float*)d_in[2];
  float* out = (float*)d_out;

  const int M = in_sizes[0] / (KDIM + 1);        // 1024
  const int V = in_sizes[1] / KDIM;              // 50257
  const int Vpad = (V + BN - 1) & ~(BN - 1);     // 50432

  // ws: wt bf16 [96*Vpad*8] | xt bf16 [96*1024*8] | cw f32 [Vpad] | tx f32 [M]
  char* ws = (char*)d_ws;
  ushort_t* wt = (ushort_t*)ws;
  ushort_t* xt = (ushort_t*)(ws + (size_t)GQ * Vpad * 8 * 2);
  float* cw = (float*)(ws + (size_t)GQ * Vpad * 8 * 2 + (size_t)GQ * 1024 * 8 * 2);
  float* tx = cw + Vpad;

  prep_x_kernel<<<dim3(M), dim3(256), 0, stream>>>(h, xt, tx);
  prep_w_kernel<<<dim3(Vpad / 8), dim3(256), 0, stream>>>(w, wt, cw, V, Vpad);

  const int nwg = (M / BM) * (Vpad / BN);        // 8 * 197 = 1576 (div by 8)
  gemm_kernel<<<dim3(nwg), dim3(256), 0, stream>>>(
      xt, wt, tx, cw, ls, out, V, Vpad, nwg / 8);
}

// Round 9
// 214.786 us; speedup vs baseline: 1.1533x; 1.1533x over previous
//
#include <hip/hip_runtime.h>
#include <hip/hip_bf16.h>
#include <cstdint>
#include <cstddef>

typedef __attribute__((ext_vector_type(4))) float f32x4;
typedef __attribute__((ext_vector_type(8))) short bf16x8;
typedef unsigned short ushort_t;

#define KDIM 768
#define GQ 96       // KDIM/8 granules
#define BM 128
#define BN 256
#define BK 32
#define NKT 24      // 768/32

static __device__ __forceinline__ float sani(float x) {
  if (__builtin_isnan(x)) return 0.0f;
  if (__builtin_isinf(x)) return x > 0.0f ? 1.0e4f : -1.0e4f;
  return x;
}

static __device__ __forceinline__ unsigned short f2bf(float x) {
  unsigned u = __builtin_bit_cast(unsigned, x);
  unsigned r = 0x7FFFu + ((u >> 16) & 1u);
  return (unsigned short)((u + r) >> 16);
}

// xl: PLAIN row-major [1024][768] bf16 (A; GEMM stages via per-lane
//     pre-swizzled global sources -> R7's verified 0-conflict LDS layout).
// wt: K-major-tiled [g 0..95][Vpad rows][8] bf16 (B; direct global->reg,
//     16 consecutive rows x 16B = coalesced 256B segments per quarter).

__global__ __launch_bounds__(256) void prep_x_kernel(
    const float* __restrict__ h, ushort_t* __restrict__ xl,
    float* __restrict__ tx) {
  const int row = blockIdx.x;
  const int t = threadIdx.x;
  const float* src = h + (size_t)row * (KDIM + 1) + 1;  // skip time comp
  float v0 = sani(src[t]);
  float v1 = sani(src[t + 256]);
  float v2 = sani(src[t + 512]);
  float ss = v0 * v0 + v1 * v1 + v2 * v2;
#pragma unroll
  for (int off = 32; off > 0; off >>= 1) ss += __shfl_down(ss, off);
  __shared__ float red[4];
  if ((t & 63) == 0) red[t >> 6] = ss;
  __syncthreads();
  if (t == 0) {
    float total = red[0] + red[1] + red[2] + red[3];
    tx[row] = sqrtf(1.0f + total);
  }
  ushort_t* dst = xl + (size_t)row * KDIM;
  dst[t]       = f2bf(v0);
  dst[t + 256] = f2bf(v1);
  dst[t + 512] = f2bf(v2);
}

__global__ __launch_bounds__(256) void prep_w_kernel(
    const float* __restrict__ w, ushort_t* __restrict__ wt,
    float* __restrict__ cw, int V, int Vpad) {
  __shared__ float fs[8 * KDIM];  // 24 KB
  __shared__ float redv[8], scs[8];
  const int t = threadIdx.x;
  const int r = t >> 5, j = t & 31;
  const int row = blockIdx.x * 8 + r;
  const bool valid = row < V;
  const float* src = w + (size_t)row * KDIM;
  float ss = 0.0f;
#pragma unroll
  for (int k = 0; k < 24; ++k) {
    float v = valid ? src[j + 32 * k] : 0.0f;
    fs[r * KDIM + j + 32 * k] = v;
    ss = fmaf(v, v, ss);
  }
#pragma unroll
  for (int m = 16; m > 0; m >>= 1) ss += __shfl_xor(ss, m);
  if (j == 0) redv[r] = ss;
  __syncthreads();
  if (t < 8) {
    const int rw = blockIdx.x * 8 + t;
    float rr = sqrtf(redv[t]);
    float rc = fminf(rr, 3.0f);
    float e = expf(rc), ei = 1.0f / e;
    scs[t] = (rw < V) ? 0.5f * (e - ei) / fmaxf(rr, 1e-8f) : 0.0f;
    cw[rw] = (rw < V) ? sani(0.5f * (e + ei)) : 0.0f;
  }
  __syncthreads();
#pragma unroll
  for (int p = 0; p < 3; ++p) {
    const int c = t + 256 * p;   // 768 chunks: g = c>>3, local row = c&7
    const int g = c >> 3, rl = c & 7;
    const float sc = scs[rl];
    ushort_t pk[8];
#pragma unroll
    for (int e = 0; e < 8; ++e)
      pk[e] = f2bf(sani(fs[rl * KDIM + g * 8 + e] * sc));
    *(uint4*)&wt[((size_t)g * Vpad + blockIdx.x * 8 + rl) * 8] =
        *(const uint4*)pk;
  }
}

#define GLD16(gp, sp)                                               \
  __builtin_amdgcn_global_load_lds(                                 \
      (const __attribute__((address_space(1))) void*)(gp),          \
      (__attribute__((address_space(3))) void*)(sp), 16, 0, 0)

// Hybrid GEMM: 4 waves of 128Mx64N (block 128x256), BK=32.
// A: ring-3 LDS (3 x 8KB), R7-verified swizzled layout (0 conflicts),
//    staged 2 tiles ahead via global_load_lds.
// B: direct global->reg from K-major wt, double-buffered 1 tile ahead.
// A ds_reads register-double-buffered: READS(t+1) issued before MFMA(t),
// gated by counted lgkmcnt(8). Counted vmcnt(6) in steady state (never 0).
__global__ __launch_bounds__(256, 2) void gemm_kernel(
    const ushort_t* __restrict__ xl, const ushort_t* __restrict__ wt,
    const float* __restrict__ tx, const float* __restrict__ cw,
    const float* __restrict__ ls, float* __restrict__ out,
    int V, int Vpad, int nwg8) {
  __shared__ ushort_t lds[3 * 4096];  // 3 slots x 8 KB (A only)

  const int tid = threadIdx.x;
  const int lane = tid & 63;
  const int wid = tid >> 6;  // 0..3: wave owns 64 N-cols
  const int l15 = lane & 15;
  const int lq = lane >> 4;  // 0..3

  // chunked XCD swizzle (nwg % 8 == 0)
  const int g = blockIdx.x;
  const int L = (g & 7) * nwg8 + (g >> 3);
  const int bm = L & 7;   // 8 M-tiles; consecutive L share bn
  const int bn = L >> 3;

  const int a_row0 = bm * BM;
  const int b_row0 = bn * BN + wid * 64;

  // ---- A staging sources (inverse of swizzled LDS layout; R7-verified) ----
  const int ggl = (lane & 7) ^ (lane >> 3);
  const int rl = 2 * (lane >> 3) + (ggl >> 2);
  const int cg = (ggl & 3) * 8;
  const ushort_t* pA0 = xl + (size_t)(a_row0 + 16 * wid + rl) * KDIM + cg;
  const ushort_t* pA1 = xl + (size_t)(a_row0 + 16 * (wid + 4) + rl) * KDIM + cg;

  // ---- A ds_read offsets (ushort elements) ----
  const int rphys = l15 >> 1;
  const int gph = (((l15 & 1) << 2) + lq) ^ rphys;
  const int aoff = rphys * 64 + gph * 8;

  // ---- B fragment base (K-major wt) ----
  const ushort_t* bp = wt + ((size_t)lq * Vpad + b_row0 + l15) * 8;
  const size_t BSTEP = (size_t)4 * Vpad * 8;  // 4 granules per K-step

  f32x4 acc[8][4];
#pragma unroll
  for (int i = 0; i < 8; ++i)
#pragma unroll
    for (int j = 0; j < 4; ++j) acc[i][j] = (f32x4){0.f, 0.f, 0.f, 0.f};

  bf16x8 afA[8], afB[8], bfA[4], bfB[4];

#define LOADB(T_, D_)                                                         \
  {                                                                           \
    const ushort_t* p_ = bp + (size_t)(T_) * BSTEP;                           \
    D_[0] = *(const bf16x8*)(p_);                                             \
    D_[1] = *(const bf16x8*)(p_ + 128);                                       \
    D_[2] = *(const bf16x8*)(p_ + 256);                                       \
    D_[3] = *(const bf16x8*)(p_ + 384);                                       \
  }

#define STAGE_A(T_, S_)                                                       \
  {                                                                           \
    GLD16(pA0 + (T_) * BK, &lds[(S_) * 4096 + wid * 512]);                    \
    GLD16(pA1 + (T_) * BK, &lds[(S_) * 4096 + (wid + 4) * 512]);              \
  }

#define READS_A(S_, D_)                                                       \
  _Pragma("unroll") for (int mi = 0; mi < 8; ++mi)                            \
      D_[mi] = *(const bf16x8*)&lds[(S_) * 4096 + mi * 512 + aoff];

#define MFMA32(AF_, BF_)                                                      \
  __builtin_amdgcn_s_setprio(1);                                              \
  _Pragma("unroll") for (int mi = 0; mi < 8; ++mi)                            \
    _Pragma("unroll") for (int ni = 0; ni < 4; ++ni)                          \
        acc[mi][ni] = __builtin_amdgcn_mfma_f32_16x16x32_bf16(                \
            BF_[ni], AF_[mi], acc[mi][ni], 0, 0, 0);                          \
  __builtin_amdgcn_s_setprio(0);

#define SBAR __builtin_amdgcn_sched_barrier(0)
#define BAR __builtin_amdgcn_s_barrier()

  // BODY(t): issue B(t+1)->NB, stage A(t+2)->slot S2, certify {B(t),A(t+1)}
  // (vmcnt(6)), barrier, issue A-reads(t+1) from slot S1 -> NA, gate
  // lgkmcnt(8) (A-reads(t) done), MFMA(t) on CA/CB, end barrier (certifies
  // cross-wave reads-before-overwrite for the ring).
#define BODY(T_, S1_, S2_, CA_, CB_, NA_, NB_)                                \
  {                                                                           \
    LOADB((T_) + 1, NB_);                                                     \
    SBAR;                                                                     \
    STAGE_A((T_) + 2, S2_);                                                   \
    SBAR;                                                                     \
    asm volatile("s_waitcnt vmcnt(6)" ::: "memory");                          \
    BAR;                                                                      \
    READS_A(S1_, NA_);                                                        \
    SBAR;                                                                     \
    asm volatile("s_waitcnt lgkmcnt(8)" ::: "memory");                        \
    SBAR;                                                                     \
    MFMA32(CA_, CB_);                                                         \
    BAR;                                                                      \
  }

  // prologue: B(0), A(0), A(1); certify B(0),A(0); read A(0) frags
  LOADB(0, bfA);
  SBAR;
  STAGE_A(0, 0);
  STAGE_A(1, 1);
  SBAR;
  asm volatile("s_waitcnt vmcnt(2)" ::: "memory");
  BAR;
  READS_A(0, afA);

  // 6-body groups (slot pattern period 6), t = 0..17
#define GROUP(T0_)                                                            \
  BODY((T0_) + 0, 1, 2, afA, bfA, afB, bfB);                                  \
  BODY((T0_) + 1, 2, 0, afB, bfB, afA, bfA);                                  \
  BODY((T0_) + 2, 0, 1, afA, bfA, afB, bfB);                                  \
  BODY((T0_) + 3, 1, 2, afB, bfB, afA, bfA);                                  \
  BODY((T0_) + 4, 2, 0, afA, bfA, afB, bfB);                                  \
  BODY((T0_) + 5, 0, 1, afB, bfB, afA, bfA);

  GROUP(0)
  GROUP(6)
  GROUP(12)
  // t = 18..21
  BODY(18, 1, 2, afA, bfA, afB, bfB);
  BODY(19, 2, 0, afB, bfB, afA, bfA);
  BODY(20, 0, 1, afA, bfA, afB, bfB);
  BODY(21, 1, 2, afB, bfB, afA, bfA);
  // t = 22: B(23) only; certify B(22),A(23) (allow B(23) in flight)
  LOADB(23, bfB);
  SBAR;
  asm volatile("s_waitcnt vmcnt(4)" ::: "memory");
  BAR;
  READS_A(2, afB);
  SBAR;
  asm volatile("s_waitcnt lgkmcnt(8)" ::: "memory");
  SBAR;
  MFMA32(afA, bfA);
  BAR;
  // t = 23: drain
  asm volatile("s_waitcnt vmcnt(0) lgkmcnt(0)" ::: "memory");
  SBAR;
  MFMA32(afB, bfB);

  float tau = ls[0];
  tau = fminf(fmaxf(tau, 0.01f), 2.5f);

  // swapped-operand C/D: m = l15 (col field), n = lq*4 + j (row field)
#pragma unroll
  for (int mi = 0; mi < 8; ++mi) {
    const int mg = a_row0 + mi * 16 + l15;
    const float txm = tx[mg];
    float* orow = out + (size_t)mg * V;
#pragma unroll
    for (int ni = 0; ni < 4; ++ni) {
      const int nb = b_row0 + ni * 16 + lq * 4;
      const f32x4 cw4 = *(const f32x4*)&cw[nb];
      f32x4 v;
#pragma unroll
      for (int j = 0; j < 4; ++j)
        v[j] = (acc[mi][ni][j] - txm * cw4[j]) * tau;
      if (nb + 3 < V) {
        __builtin_memcpy(&orow[nb], &v, 16);
      } else {
#pragma unroll
        for (int j = 0; j < 4; ++j)
          if (nb + j < V) orow[nb + j] = v[j];
      }
    }
  }
#undef LOADB
#undef STAGE_A
#undef READS_A
#undef MFMA32
#undef BODY
#undef GROUP
#undef SBAR
#undef BAR
}

extern "C" void kernel_launch(void* const* d_in, const int* in_sizes, int n_in,
                              void* d_out, int out_size, void* d_ws, size_t ws_size,
                              hipStream_t stream) {
  const float* h = (const float*)d_in[0];
  const float* w = (const float*)d_in[1];
  const float* ls = (const float*)d_in[2];
  float* out = (float*)d_out;

  const int M = in_sizes[0] / (KDIM + 1);        // 1024
  const int V = in_sizes[1] / KDIM;              // 50257
  const int Vpad = (V + BN - 1) & ~(BN - 1);     // 50432

  // ws: wt bf16 [96*Vpad*8] | xl bf16 [M*768] | cw f32 [Vpad] | tx f32 [M]
  char* ws = (char*)d_ws;
  ushort_t* wt = (ushort_t*)ws;
  ushort_t* xl = (ushort_t*)(ws + (size_t)GQ * Vpad * 8 * 2);
  float* cw = (float*)(ws + (size_t)GQ * Vpad * 8 * 2 + (size_t)M * KDIM * 2);
  float* tx = cw + Vpad;

  prep_x_kernel<<<dim3(M), dim3(256), 0, stream>>>(h, xl, tx);
  prep_w_kernel<<<dim3(Vpad / 8), dim3(256), 0, stream>>>(w, wt, cw, V, Vpad);

  const int nwg = (M / BM) * (Vpad / BN);        // 8 * 197 = 1576 (div by 8)
  gemm_kernel<<<dim3(nwg), dim3(256), 0, stream>>>(
      xl, wt, tx, cw, ls, out, V, Vpad, nwg / 8);
}